// Round 3
// baseline (553.480 us; speedup 1.0000x reference)
//
#include <hip/hip_runtime.h>
#include <hip/hip_bf16.h>
#include <math.h>

// Problem constants
#define BB 4
#define SS 2048
#define DD 1024
#define HH 16
#define HD 64

#define NEG_BIG (-1e30f)  // finite "-inf": exp(NEG_BIG - m) == 0

// Verified facts (rounds 0-8):
//  - float inputs fp32; OUTPUT fp32; MFMA C/D layout col=lane&15,row=quad*4+reg
//  - ws_size >= 2*NE shorts (33.5 MB) usable
//  - r7: cvt_pk + ones-MFMA denom: 575->504. r8: gll GEMM + preconvert: wash
//    => both GEMM and attn are SERIALIZATION-bound (2-barrier loops, no
//    overlap), not VALU-bound.
// Round 9:
//  - GEMM: 2-phase double-buffer (T3 minimum), ONE barrier/K-step; gll +
//    weight loads issue before MFMAs, cvt+ds_write after (T14 split).
//  - attn: 128-row q-tiles (2 groups/wave, shared B-frags: 36 MFMA/tile),
//    double-buffered K/V, single barrier/tile, T14 reg-prefetch of next tile.
//  - sigma-permuted key dim (sigma(j*16+l16)=l16*4+j) in V^T epilogue + P
//    store: P written as ds_write_b64 (kills b16 same-word conflicts).

typedef short v8s __attribute__((ext_vector_type(8)));
typedef float v4f __attribute__((ext_vector_type(4)));
typedef unsigned v2u __attribute__((ext_vector_type(2)));

__device__ inline unsigned cvt_pk_bf16(float lo, float hi) {
    unsigned r;
    asm("v_cvt_pk_bf16_f32 %0, %1, %2" : "=v"(r) : "v"(lo), "v"(hi));
    return r;
}

__device__ inline short f2bf(float f) {
    return (short)cvt_pk_bf16(f, f);
}

__device__ inline v4f v4f_zero() {
    v4f z;
    z[0] = 0.f; z[1] = 0.f; z[2] = 0.f; z[3] = 0.f;
    return z;
}

__device__ inline v8s cvt8(v4f a, v4f b) {
    union { unsigned u[4]; v8s s; } x;
    x.u[0] = cvt_pk_bf16(a[0], a[1]);
    x.u[1] = cvt_pk_bf16(a[2], a[3]);
    x.u[2] = cvt_pk_bf16(b[0], b[1]);
    x.u[3] = cvt_pk_bf16(b[2], b[3]);
    return x.s;
}

__device__ inline v8s load8f(const float* p) {
    return cvt8(*(const v4f*)p, *(const v4f*)(p + 4));
}

// Async global->LDS, 16B/lane. LDS dest wave-uniform base; lane i -> base+16i.
__device__ inline void gll16(const void* g, void* l) {
    __builtin_amdgcn_global_load_lds(
        (const __attribute__((address_space(1))) unsigned*)g,
        (__attribute__((address_space(3))) unsigned*)l, 16, 0, 0);
}

// ---------------------------------------------------------------------------
// fp32 -> bf16 elementwise (vectorized, grid-stride). n8 = elems/8.
// ---------------------------------------------------------------------------
__global__ __launch_bounds__(256) void conv_bf16_kernel(
    const float* __restrict__ in, short* __restrict__ out, int n8) {
    int i = blockIdx.x * 256 + threadIdx.x;
    const int stride = gridDim.x * 256;
    for (; i < n8; i += stride) {
        *((v8s*)out + i) = load8f(in + (size_t)i * 8);
    }
}

// ---------------------------------------------------------------------------
// NT GEMM: C[M,N] = A[M,K] * B[N,K]^T + bias, fp32 accum, bf16 MFMA. K=1024.
// Big operand bf16 via global_load_lds; small (weights) fp32 reg-cvt.
// 2-phase double-buffered: one barrier per K-step; next-tile loads issued
// before the MFMA cluster (T14), weight cvt+ds_write after.
// MODE 0: A big bf16 [M,1024]; C bf16 [B,H,S,HD]. grid (8,64,2) fused Q+K.
// MODE 1: B big bf16 [N,1024] tokens; A = W fp32; C bf16 [B,H,HD,S] with
//         sigma-permuted token index within each 64-tile. grid (64,8).
// MODE 3: A big bf16 ws [B,H,S,HD] remap; C fp32 row-major. grid (8,64).
// ---------------------------------------------------------------------------
template <int MODE>
__global__ __launch_bounds__(256) void gemm_kernel(
    const void* __restrict__ Pbig, const float* __restrict__ Psml,
    const float* __restrict__ Pbias, void* __restrict__ PC,
    const void* __restrict__ Pbig2, const float* __restrict__ Psml2,
    const float* __restrict__ Pbias2, void* __restrict__ PC2) {
    __shared__ short sA[2][128 * 32];
    __shared__ short sB[2][128 * 32];

    const int tid = threadIdx.x;
    const int lane = tid & 63;
    const int wave = tid >> 6;
    const int quad = lane >> 4;
    const int l16 = lane & 15;
    const int wm = wave >> 1;
    const int wn = wave & 1;

    const void* Big = Pbig;
    const float* Sml = Psml;
    const float* bias = Pbias;
    void* Cv = PC;
    if (MODE == 0 && blockIdx.z == 1) {
        Big = Pbig2; Sml = Psml2; bias = Pbias2; Cv = PC2;
    }

    int bx, by;
    if (MODE != 1) {
        // group same-m-panel blocks (8 n-tiles) per XCD
        int b = blockIdx.x + (blockIdx.y << 3);
        int l = ((b & 7) << 6) + (b >> 3);
        bx = l & 7;
        by = l >> 3;
    } else {
        // group same-n-panel blocks (8 m-tiles) per XCD
        int L = blockIdx.x + blockIdx.y * 64;
        int xcd = L & 7, slot = L >> 3;
        bx = xcd * 8 + (slot & 7);
        by = slot >> 3;
    }
    const int m0 = by * 128;
    const int n0 = bx * 128;

    // big-operand gll addressing
    const int grow = (wave << 5) + (lane >> 2);  // row in tile (+16 for 2nd)
    const int gcol = (lane & 3) << 3;
    const short* BigS = (const short*)Big;
    size_t gbase0, gbase1;
    if (MODE == 3) {
        int ma = m0 + grow, mb = m0 + grow + 16;
        gbase0 = ((size_t)((ma >> 11) * HH) * SS + (ma & 2047)) * HD;
        gbase1 = ((size_t)((mb >> 11) * HH) * SS + (mb & 2047)) * HD;
    } else {
        int r0 = ((MODE == 1) ? n0 : m0) + grow;
        gbase0 = (size_t)r0 * 1024 + gcol;
        gbase1 = gbase0 + (size_t)16 * 1024;
    }
    const int ldoff = wave << 10;  // wave-uniform LDS base (shorts)

    // small-operand (weights) reg-stage addressing
    const int sml_base = (MODE == 1) ? m0 : n0;
    const int idx0 = tid << 3, idx1 = (256 + tid) << 3;
    const float* Wsrc0 = Sml + (size_t)(sml_base + (idx0 >> 5)) * 1024 + (idx0 & 31);
    const float* Wsrc1 = Sml + (size_t)(sml_base + (idx1 >> 5)) * 1024 + (idx1 & 31);

    v4f acc[4][4];
#pragma unroll
    for (int i = 0; i < 4; i++)
#pragma unroll
        for (int j = 0; j < 4; j++) acc[i][j] = v4f_zero();

    // prologue: stage k0=0 into buf 0
    {
        short* sBigT = (MODE == 1) ? sB[0] : sA[0];
        short* sSmlT = (MODE == 1) ? sA[0] : sB[0];
        if (MODE == 3) {
            size_t hoff = (size_t)gcol;
            gll16(BigS + gbase0 + hoff, sBigT + ldoff);
            gll16(BigS + gbase1 + hoff, sBigT + ldoff + 512);
        } else {
            gll16(BigS + gbase0, sBigT + ldoff);
            gll16(BigS + gbase1, sBigT + ldoff + 512);
        }
        v4f w00 = *(const v4f*)Wsrc0, w01 = *(const v4f*)(Wsrc0 + 4);
        v4f w10 = *(const v4f*)Wsrc1, w11 = *(const v4f*)(Wsrc1 + 4);
        *(v8s*)&sSmlT[idx0] = cvt8(w00, w01);
        *(v8s*)&sSmlT[idx1] = cvt8(w10, w11);
    }

    int cur = 0;
    for (int k0 = 0; k0 < 1024; k0 += 32, cur ^= 1) {
        __syncthreads();  // buf[cur] complete (drains vmcnt+lgkm)

        const int k1 = k0 + 32;
        const bool pre = (k1 < 1024);
        v4f w00, w01, w10, w11;
        if (pre) {
            // issue next-tile loads BEFORE compute (T14)
            short* sBigN = (MODE == 1) ? sB[cur ^ 1] : sA[cur ^ 1];
            if (MODE == 3) {
                size_t hoff = (size_t)(k1 >> 6) * (SS * HD) + (k1 & 63) + gcol;
                gll16(BigS + gbase0 + hoff, sBigN + ldoff);
                gll16(BigS + gbase1 + hoff, sBigN + ldoff + 512);
            } else {
                gll16(BigS + gbase0 + k1, sBigN + ldoff);
                gll16(BigS + gbase1 + k1, sBigN + ldoff + 512);
            }
            w00 = *(const v4f*)(Wsrc0 + k1);
            w01 = *(const v4f*)(Wsrc0 + k1 + 4);
            w10 = *(const v4f*)(Wsrc1 + k1);
            w11 = *(const v4f*)(Wsrc1 + k1 + 4);
        }

        v8s af[4], bfr[4];
#pragma unroll
        for (int i = 0; i < 4; i++)
            af[i] = *(const v8s*)&sA[cur][(wm * 64 + i * 16 + l16) * 32 + quad * 8];
#pragma unroll
        for (int j = 0; j < 4; j++)
            bfr[j] = *(const v8s*)&sB[cur][(wn * 64 + j * 16 + l16) * 32 + quad * 8];
        __builtin_amdgcn_s_setprio(1);
#pragma unroll
        for (int i = 0; i < 4; i++)
#pragma unroll
            for (int j = 0; j < 4; j++)
                acc[i][j] = __builtin_amdgcn_mfma_f32_16x16x32_bf16(
                    af[i], bfr[j], acc[i][j], 0, 0, 0);
        __builtin_amdgcn_s_setprio(0);

        if (pre) {
            short* sSmlN = (MODE == 1) ? sA[cur ^ 1] : sB[cur ^ 1];
            *(v8s*)&sSmlN[idx0] = cvt8(w00, w01);
            *(v8s*)&sSmlN[idx1] = cvt8(w10, w11);
        }
    }

    // Epilogue: C/D layout col = lane&15, row = quad*4 + reg
#pragma unroll
    for (int i = 0; i < 4; i++) {
#pragma unroll
        for (int j = 0; j < 4; j++) {
#pragma unroll
            for (int r = 0; r < 4; r++) {
                int ml = wm * 64 + i * 16 + quad * 4 + r;
                int nl = wn * 64 + j * 16 + l16;
                int m = m0 + ml;
                int n = n0 + nl;
                float v = acc[i][j][r];
                if (MODE == 0) {
                    v += bias[n];
                    int b = m >> 11, s = m & 2047, h = n >> 6, d = n & 63;
                    ((short*)Cv)[(((size_t)(b * HH + h) * SS + s) << 6) + d] =
                        f2bf(v);
                } else if (MODE == 1) {
                    v += bias[m];
                    int h = m >> 6, d = m & 63, b = n >> 11, s = n & 2047;
                    // sigma-permute token index within its 64-tile:
                    // sigma(j*16+l16) = l16*4 + j  (consistent with P store)
                    int sp = (s & ~63) | ((s & 15) << 2) | ((s >> 4) & 3);
                    ((short*)Cv)[((size_t)(b * HH + h) * HD + d) * SS + sp] =
                        f2bf(v);
                } else {
                    v += bias[n];
                    ((float*)Cv)[(size_t)m * 1024 + n] = v;
                }
            }
        }
    }
}

// ---------------------------------------------------------------------------
// Flash attention (causal). Grid: (S/128, B*H). 256 thr = 4 waves; each wave
// owns 32 q-rows (2 groups of 16, sharing K/V B-frags -> 36 MFMA per tile).
// K/V double-buffered in LDS, ONE barrier per tile; next tile global->reg
// loads issued before QK^T, LDS-written after PV (T14). P stored per-wave in
// sigma layout (col = l16*4+j) via ds_write_b64; V^T comes sigma-permuted
// from the projection, so the PV contraction is consistent.
// ---------------------------------------------------------------------------
__global__ __launch_bounds__(256) void attn_kernel(
    short* __restrict__ QO, const short* __restrict__ Kt,
    const short* __restrict__ Vt) {
    constexpr int LDR = 72;
    __shared__ short sK[2][64 * LDR];
    __shared__ short sV[2][64 * LDR];
    __shared__ short sP[4][16 * LDR];

    const int tid = threadIdx.x;
    const int lane = tid & 63;
    const int wave = tid >> 6;
    const int quad = lane >> 4;
    const int l16 = lane & 15;
    const int qt = (int)gridDim.x - 1 - (int)blockIdx.x;  // heavy blocks first
    const int bh = blockIdx.y;

    short* Qh = QO + (size_t)bh * SS * HD;
    const short* Kh = Kt + (size_t)bh * SS * HD;
    const short* Vh = Vt + (size_t)bh * HD * SS;

    // staging coords: 256 threads cover rows 0..31 (p=0) / 32..63 (p=1)
    const int srow = tid >> 3;
    const int scol = (tid & 7) << 3;

    const int qbase = qt * 128 + wave * 32;
    v8s qf[2][2];
#pragma unroll
    for (int g = 0; g < 2; g++) {
        const short* qp = &Qh[(size_t)(qbase + g * 16 + l16) * HD];
        qf[g][0] = *(const v8s*)&qp[quad * 8];
        qf[g][1] = *(const v8s*)&qp[32 + quad * 8];
    }

    v8s onesb;
#pragma unroll
    for (int i = 0; i < 8; i++) onesb[i] = (short)0x3F80;  // bf16 1.0

    v4f o[2][4];
#pragma unroll
    for (int g = 0; g < 2; g++)
#pragma unroll
        for (int j = 0; j < 4; j++) o[g][j] = v4f_zero();
    v4f oSum[2];
    oSum[0] = v4f_zero();
    oSum[1] = v4f_zero();
    float mOld[2][4];
#pragma unroll
    for (int g = 0; g < 2; g++)
#pragma unroll
        for (int r = 0; r < 4; r++) mOld[g][r] = NEG_BIG;

    const int ktmax = 2 * qt + 1;

    // prologue: stage tile 0 into buf 0
    {
        v8s a0 = *(const v8s*)&Kh[(size_t)srow * HD + scol];
        v8s a1 = *(const v8s*)&Kh[(size_t)(srow + 32) * HD + scol];
        v8s b0 = *(const v8s*)&Vh[(size_t)srow * SS + scol];
        v8s b1 = *(const v8s*)&Vh[(size_t)(srow + 32) * SS + scol];
        *(v8s*)&sK[0][srow * LDR + scol] = a0;
        *(v8s*)&sK[0][(srow + 32) * LDR + scol] = a1;
        *(v8s*)&sV[0][srow * LDR + scol] = b0;
        *(v8s*)&sV[0][(srow + 32) * LDR + scol] = b1;
    }

    int cur = 0;
    for (int kt = 0; kt <= ktmax; kt++, cur ^= 1) {
        __syncthreads();  // buf[cur] ready (drains prior lgkm)

        const bool pre = (kt < ktmax);
        v8s pk0, pk1, pv0, pv1;
        if (pre) {  // issue next-tile loads now; consumed after PV (T14)
            int kb = (kt + 1) * 64;
            pk0 = *(const v8s*)&Kh[(size_t)(kb + srow) * HD + scol];
            pk1 = *(const v8s*)&Kh[(size_t)(kb + srow + 32) * HD + scol];
            pv0 = *(const v8s*)&Vh[(size_t)srow * SS + kb + scol];
            pv1 = *(const v8s*)&Vh[(size_t)(srow + 32) * SS + kb + scol];
        }

        // QK^T for both groups, shared B-frags
        v4f sc[2][4];
        __builtin_amdgcn_s_setprio(1);
#pragma unroll
        for (int j = 0; j < 4; j++) {
            v8s b0 = *(const v8s*)&sK[cur][(j * 16 + l16) * LDR + quad * 8];
            v8s b1 = *(const v8s*)&sK[cur][(j * 16 + l16) * LDR + 32 + quad * 8];
#pragma unroll
            for (int g = 0; g < 2; g++) {
                v4f t = __builtin_amdgcn_mfma_f32_16x16x32_bf16(
                    qf[g][0], b0, v4f_zero(), 0, 0, 0);
                sc[g][j] = __builtin_amdgcn_mfma_f32_16x16x32_bf16(
                    qf[g][1], b1, t, 0, 0, 0);
            }
        }
        __builtin_amdgcn_s_setprio(0);

#pragma unroll
        for (int g = 0; g < 2; g++) {
            const int gb = qbase + g * 16;
            const int qgb = gb + quad * 4;
            const bool gate = (kt * 64 + 63) > gb;  // any masking possible?
            float x[4][4];
#pragma unroll
            for (int j = 0; j < 4; j++) {
#pragma unroll
                for (int r = 0; r < 4; r++) {
                    float v = sc[g][j][r] * 0.125f;
                    if (gate) {
                        int kg = kt * 64 + j * 16 + l16;
                        if (kg > qgb + r) v = NEG_BIG;
                    }
                    x[j][r] = v;
                }
            }

            float mNew[4], alpha[4];
#pragma unroll
            for (int r = 0; r < 4; r++) {
                float t = fmaxf(fmaxf(x[0][r], x[1][r]), fmaxf(x[2][r], x[3][r]));
#pragma unroll
                for (int off = 8; off >= 1; off >>= 1)
                    t = fmaxf(t, __shfl_xor(t, off));
                mNew[r] = fmaxf(mOld[g][r], t);
                alpha[r] = __expf(mOld[g][r] - mNew[r]);
                mOld[g][r] = mNew[r];
            }

            // P -> sP (sigma layout: row = q-row-in-group, col = l16*4 + j)
            short* Pw = sP[wave];
#pragma unroll
            for (int r = 0; r < 4; r++) {
                float p0 = __expf(x[0][r] - mNew[r]);
                float p1 = __expf(x[1][r] - mNew[r]);
                float p2 = __expf(x[2][r] - mNew[r]);
                float p3 = __expf(x[3][r] - mNew[r]);
                v2u w;
                w[0] = cvt_pk_bf16(p0, p1);
                w[1] = cvt_pk_bf16(p2, p3);
                *(v2u*)&Pw[(quad * 4 + r) * LDR + l16 * 4] = w;
            }
#pragma unroll
            for (int j = 0; j < 4; j++)
#pragma unroll
                for (int r = 0; r < 4; r++) o[g][j][r] *= alpha[r];
#pragma unroll
            for (int r = 0; r < 4; r++) oSum[g][r] *= alpha[r];

            // PV (+ ones-MFMA denominator); same-wave ds order guards sP reuse
            v8s pa0 = *(const v8s*)&Pw[l16 * LDR + quad * 8];
            v8s pa1 = *(const v8s*)&Pw[l16 * LDR + 32 + quad * 8];
            __builtin_amdgcn_s_setprio(1);
#pragma unroll
            for (int j = 0; j < 4; j++) {
                v8s v0 = *(const v8s*)&sV[cur][(j * 16 + l16) * LDR + quad * 8];
                v8s v1 = *(const v8s*)&sV[cur][(j * 16 + l16) * LDR + 32 + quad * 8];
                o[g][j] = __builtin_amdgcn_mfma_f32_16x16x32_bf16(
                    pa0, v0, o[g][j], 0, 0, 0);
                o[g][j] = __builtin_amdgcn_mfma_f32_16x16x32_bf16(
                    pa1, v1, o[g][j], 0, 0, 0);
            }
            oSum[g] = __builtin_amdgcn_mfma_f32_16x16x32_bf16(
                pa0, onesb, oSum[g], 0, 0, 0);
            oSum[g] = __builtin_amdgcn_mfma_f32_16x16x32_bf16(
                pa1, onesb, oSum[g], 0, 0, 0);
            __builtin_amdgcn_s_setprio(0);
        }

        if (pre) {  // write prefetched tile into the other buffer
            int nxt = cur ^ 1;
            *(v8s*)&sK[nxt][srow * LDR + scol] = pk0;
            *(v8s*)&sK[nxt][(srow + 32) * LDR + scol] = pk1;
            *(v8s*)&sV[nxt][srow * LDR + scol] = pv0;
            *(v8s*)&sV[nxt][(srow + 32) * LDR + scol] = pv1;
        }
    }

    // Normalize; store O over this block's own Q rows
#pragma unroll
    for (int g = 0; g < 2; g++) {
#pragma unroll
        for (int r = 0; r < 4; r++) {
            float inv = 1.f / oSum[g][r];
            int s = qbase + g * 16 + quad * 4 + r;
#pragma unroll
            for (int j = 0; j < 4; j++) {
                float v = o[g][j][r] * inv;
                Qh[(size_t)s * HD + j * 16 + l16] = f2bf(v);
            }
        }
    }
}

// ---------------------------------------------------------------------------
extern "C" void kernel_launch(void* const* d_in, const int* in_sizes, int n_in,
                              void* d_out, int out_size, void* d_ws, size_t ws_size,
                              hipStream_t stream) {
    const float* query = (const float*)d_in[0];
    const float* key_ = (const float*)d_in[1];
    const float* value = (const float*)d_in[2];
    const float* Wq = (const float*)d_in[3];
    const float* bq = (const float*)d_in[4];
    const float* Wk = (const float*)d_in[5];
    const float* bk = (const float*)d_in[6];
    const float* Wv = (const float*)d_in[7];
    const float* bv = (const float*)d_in[8];
    const float* Wo = (const float*)d_in[9];
    const float* bo = (const float*)d_in[10];
    float* out = (float*)d_out;

    const size_t NE = (size_t)BB * SS * DD;

    // Memory plan: ws = qw | kw ; d_out = qx -> vw | kx -> vx (stream-ordered)
    short* qx = (short*)d_out;
    short* kx = (short*)d_out + NE;
    short* vx = (short*)d_out + NE;
    short* vw = (short*)d_out;
    short* qw = (short*)d_ws;
    short* kw = (short*)d_ws + NE;

    dim3 blk(256);
    const int n8 = (int)(NE / 8);
    conv_bf16_kernel<<<dim3(2048), blk, 0, stream>>>(query, qx, n8);
    conv_bf16_kernel<<<dim3(2048), blk, 0, stream>>>(key_, kx, n8);
    gemm_kernel<0><<<dim3(8, 64, 2), blk, 0, stream>>>(
        qx, Wq, bq, qw, kx, Wk, bk, kw);
    conv_bf16_kernel<<<dim3(2048), blk, 0, stream>>>(value, vx, n8);
    gemm_kernel<1><<<dim3(64, 8), blk, 0, stream>>>(
        vx, Wv, bv, vw, nullptr, nullptr, nullptr, nullptr);
    attn_kernel<<<dim3(SS / 128, BB * HH), blk, 0, stream>>>(qw, kw, vw);
    gemm_kernel<3><<<dim3(8, 64), blk, 0, stream>>>(
        qw, Wo, bo, out, nullptr, nullptr, nullptr, nullptr);
}

// Round 4
// 475.161 us; speedup vs baseline: 1.1648x; 1.1648x over previous
//
#include <hip/hip_runtime.h>
#include <hip/hip_bf16.h>
#include <math.h>

// Problem constants
#define BB 4
#define SS 2048
#define DD 1024
#define HH 16
#define HD 64

#define NEG_BIG (-1e30f)  // finite "-inf": exp(NEG_BIG - m) == 0

// Verified facts (rounds 0-9):
//  - fp32 inputs, fp32 output; MFMA C/D layout col=lane&15,row=quad*4+reg
//  - ws_size >= 2*NE shorts (33.5 MB)
//  - r7 (cvt_pk, ones-MFMA denom, setprio): 575->504
//  - r8 (gll big operand, preconvert acts): wash => GEMM not cvt-bound
//  - r9 (2-phase dbuf GEMM + 128-row attn dbuf): REGRESSED 509->553
//    => source-level pipelining of 2-barrier loops is neutral/negative
//       (matches learn_hip m99/m100/m131-141). Remove work, don't pipeline.
// Round 10:
//  - attn reverted to r8 verbatim (known 200us).
//  - GEMM reverted to r8 single-buffer 2-barrier loop; weights pre-converted
//    to bf16 so Q/K/out projections stage BOTH operands via global_load_lds
//    (m97 recipe: zero VALU in K-loop). V-proj: gll weight + reg-stage fp32
//    value (saves the 16MB vx conversion).
//  - Memory plan (shorts): DO0=d_out[0:NE], DO1=d_out[NE:2NE],
//    WS0=ws[0:NE], WS1=ws[NE:2NE]; every launch's read/write sets verified
//    disjoint (see kernel_launch comments).

typedef short v8s __attribute__((ext_vector_type(8)));
typedef float v4f __attribute__((ext_vector_type(4)));

__device__ inline unsigned cvt_pk_bf16(float lo, float hi) {
    unsigned r;
    asm("v_cvt_pk_bf16_f32 %0, %1, %2" : "=v"(r) : "v"(lo), "v"(hi));
    return r;
}

__device__ inline short f2bf(float f) {
    return (short)cvt_pk_bf16(f, f);
}

__device__ inline v4f v4f_zero() {
    v4f z;
    z[0] = 0.f; z[1] = 0.f; z[2] = 0.f; z[3] = 0.f;
    return z;
}

__device__ inline v8s cvt8(v4f a, v4f b) {
    union { unsigned u[4]; v8s s; } x;
    x.u[0] = cvt_pk_bf16(a[0], a[1]);
    x.u[1] = cvt_pk_bf16(a[2], a[3]);
    x.u[2] = cvt_pk_bf16(b[0], b[1]);
    x.u[3] = cvt_pk_bf16(b[2], b[3]);
    return x.s;
}

__device__ inline v8s load8f(const float* p) {
    return cvt8(*(const v4f*)p, *(const v4f*)(p + 4));
}

// Async global->LDS, 16B/lane. LDS dest wave-uniform base; lane i -> base+16i.
__device__ inline void gll16(const void* g, void* l) {
    __builtin_amdgcn_global_load_lds(
        (const __attribute__((address_space(1))) unsigned*)g,
        (__attribute__((address_space(3))) unsigned*)l, 16, 0, 0);
}

// ---------------------------------------------------------------------------
// fp32 -> bf16 elementwise (vectorized, grid-stride). n8 = elems/8.
// ---------------------------------------------------------------------------
__global__ __launch_bounds__(256) void conv_bf16_kernel(
    const float* __restrict__ in, short* __restrict__ out, int n8) {
    int i = blockIdx.x * 256 + threadIdx.x;
    const int stride = gridDim.x * 256;
    for (; i < n8; i += stride) {
        *((v8s*)out + i) = load8f(in + (size_t)i * 8);
    }
}

// ---------------------------------------------------------------------------
// NT GEMM: C[M,N] = A[M,K] * B[N,K]^T + bias, fp32 accum, bf16 MFMA. K=1024.
// Single-buffer, 2 barriers per K-step (m97 structure).
// MODE 0: A act bf16 gll [8192,1024]; B wt bf16 gll; C bf16 [B,H,S,HD]. (8,64)
// MODE 1: A wt bf16 gll [1024,1024]; B value fp32 reg-staged [8192,1024];
//         C bf16 [B,H,HD,S]. grid (64,8).
// MODE 3: A O-bf16 ws remap gll; B wt bf16 gll; C fp32 row-major. (8,64)
// Tiles: BM=BN=128, BK=32. 256 thr = 4 waves (2x2), 64x64 per wave.
// ---------------------------------------------------------------------------
template <int MODE>
__global__ __launch_bounds__(256) void gemm_kernel(
    const void* __restrict__ Av, const void* __restrict__ Bv,
    const float* __restrict__ bias, void* __restrict__ Cv) {
    __shared__ short sA[128 * 32];
    __shared__ short sB[128 * 32];

    const int tid = threadIdx.x;
    const int lane = tid & 63;
    const int wave = tid >> 6;
    const int quad = lane >> 4;
    const int l16 = lane & 15;
    const int wm = wave >> 1;
    const int wn = wave & 1;

    int bx, by;
    if (MODE != 1) {
        // XCD swizzle: group the 8 n-tiles of one m-panel on one XCD
        int b = blockIdx.x + (blockIdx.y << 3);
        int l = ((b & 7) << 6) + (b >> 3);
        bx = l & 7;
        by = l >> 3;
    } else {
        bx = blockIdx.x;
        by = blockIdx.y;
    }
    const int m0 = by * 128;
    const int n0 = bx * 128;

    // gll addressing: lane i of wave w writes sX + w*1024 + i*8 shorts, which
    // is row (w*32 + i/4), col (i%4)*8 of the row-major 128x32 tile.
    const int grow = (wave << 5) + (lane >> 2);
    const int gcol = (lane & 3) << 3;
    const int ldoff = wave << 10;

    // A operand (always bf16, gll)
    const short* As = (const short*)Av;
    size_t gaA0, gaA1;
    if (MODE == 3) {
        int ma = m0 + grow, mb = m0 + grow + 16;
        gaA0 = ((size_t)((ma >> 11) * HH) * SS + (ma & 2047)) * HD;
        gaA1 = ((size_t)((mb >> 11) * HH) * SS + (mb & 2047)) * HD;
    } else {
        gaA0 = (size_t)(m0 + grow) * 1024 + gcol;
        gaA1 = gaA0 + (size_t)16 * 1024;
    }

    // B operand
    const short* Bs = (const short*)Bv;     // modes 0/3: bf16 weight, gll
    const float* Bf = (const float*)Bv;     // mode 1: fp32 value, reg-staged
    size_t gaB0 = 0, gaB1 = 0;
    if (MODE != 1) {
        gaB0 = (size_t)(n0 + grow) * 1024 + gcol;
        gaB1 = gaB0 + (size_t)16 * 1024;
    }
    const int idx0 = tid << 3, idx1 = (256 + tid) << 3;
    const float* Bsrc0 = (MODE == 1)
        ? Bf + (size_t)(n0 + (idx0 >> 5)) * 1024 + (idx0 & 31) : nullptr;
    const float* Bsrc1 = (MODE == 1)
        ? Bf + (size_t)(n0 + (idx1 >> 5)) * 1024 + (idx1 & 31) : nullptr;

    v4f acc[4][4];
#pragma unroll
    for (int i = 0; i < 4; i++)
#pragma unroll
        for (int j = 0; j < 4; j++) acc[i][j] = v4f_zero();

    for (int k0 = 0; k0 < 1024; k0 += 32) {
        __syncthreads();
        if (MODE == 3) {
            size_t hoff = (size_t)(k0 >> 6) * (SS * HD) + (k0 & 63) + gcol;
            gll16(As + gaA0 + hoff, sA + ldoff);
            gll16(As + gaA1 + hoff, sA + ldoff + 512);
        } else {
            gll16(As + gaA0 + k0, sA + ldoff);
            gll16(As + gaA1 + k0, sA + ldoff + 512);
        }
        if (MODE == 1) {
            *(v8s*)&sB[idx0] = load8f(Bsrc0 + k0);
            *(v8s*)&sB[idx1] = load8f(Bsrc1 + k0);
        } else {
            gll16(Bs + gaB0 + k0, sB + ldoff);
            gll16(Bs + gaB1 + k0, sB + ldoff + 512);
        }
        __syncthreads();

        v8s af[4], bfr[4];
#pragma unroll
        for (int i = 0; i < 4; i++)
            af[i] = *(const v8s*)&sA[(wm * 64 + i * 16 + l16) * 32 + quad * 8];
#pragma unroll
        for (int j = 0; j < 4; j++)
            bfr[j] = *(const v8s*)&sB[(wn * 64 + j * 16 + l16) * 32 + quad * 8];
#pragma unroll
        for (int i = 0; i < 4; i++)
#pragma unroll
            for (int j = 0; j < 4; j++)
                acc[i][j] = __builtin_amdgcn_mfma_f32_16x16x32_bf16(
                    af[i], bfr[j], acc[i][j], 0, 0, 0);
    }

    // Epilogue: C/D layout col = lane&15, row = quad*4 + reg (HW-verified r6)
#pragma unroll
    for (int i = 0; i < 4; i++) {
#pragma unroll
        for (int j = 0; j < 4; j++) {
#pragma unroll
            for (int r = 0; r < 4; r++) {
                int ml = wm * 64 + i * 16 + quad * 4 + r;
                int nl = wn * 64 + j * 16 + l16;
                int m = m0 + ml;
                int n = n0 + nl;
                float v = acc[i][j][r];
                if (MODE == 0) {
                    v += bias[n];
                    int b = m >> 11, s = m & 2047, h = n >> 6, d = n & 63;
                    ((short*)Cv)[(((size_t)(b * HH + h) * SS + s) << 6) + d] =
                        f2bf(v);
                } else if (MODE == 1) {
                    v += bias[m];
                    int h = m >> 6, d = m & 63, b = n >> 11, s = n & 2047;
                    ((short*)Cv)[((size_t)(b * HH + h) * HD + d) * SS + s] =
                        f2bf(v);
                } else {
                    v += bias[n];
                    ((float*)Cv)[(size_t)m * 1024 + n] = v;
                }
            }
        }
    }
}

// ---------------------------------------------------------------------------
// Flash attention (causal, MFMA). Grid: (S/64, B*H). 256 thr = 4 waves.
// r8 version verbatim (measured 200us): ones-MFMA softmax denominator, no
// mid-barrier (sP per-wave), setprio around MFMA clusters, reversed qt order.
// ---------------------------------------------------------------------------
__global__ __launch_bounds__(256) void attn_kernel(
    short* __restrict__ QO, const short* __restrict__ Kt,
    const short* __restrict__ Vt) {
    constexpr int LDR = 64 + 8;
    __shared__ short sK[64 * LDR];
    __shared__ short sV[64 * LDR];
    __shared__ short sP[4][16 * LDR];

    const int tid = threadIdx.x;
    const int lane = tid & 63;
    const int wave = tid >> 6;
    const int quad = lane >> 4;
    const int l16 = lane & 15;
    const int qt = (int)gridDim.x - 1 - (int)blockIdx.x;
    const int bh = blockIdx.y;

    short* Qh = QO + (size_t)bh * SS * HD;
    const short* Kh = Kt + (size_t)bh * SS * HD;
    const short* Vh = Vt + (size_t)bh * HD * SS;

    const int qrow = qt * 64 + wave * 16 + l16;
    v8s qf[2];
    qf[0] = *(const v8s*)&Qh[(size_t)qrow * HD + quad * 8];
    qf[1] = *(const v8s*)&Qh[(size_t)qrow * HD + 32 + quad * 8];

    v8s onesb;
#pragma unroll
    for (int i = 0; i < 8; i++) onesb[i] = (short)0x3F80;  // bf16 1.0

    v4f o[4];
#pragma unroll
    for (int j = 0; j < 4; j++) o[j] = v4f_zero();
    v4f oSum = v4f_zero();
    float mOld[4];
#pragma unroll
    for (int r = 0; r < 4; r++) mOld[r] = NEG_BIG;

    const int qg_base = qt * 64 + wave * 16 + quad * 4;

    for (int kt = 0; kt <= qt; kt++) {
        __syncthreads();
#pragma unroll
        for (int p = 0; p < 2; p++) {
            int idx = (p * 256 + tid) * 8;
            int r = idx >> 6;
            int c = idx & 63;
            *(v8s*)&sK[r * LDR + c] =
                *(const v8s*)&Kh[(size_t)(kt * 64 + r) * HD + c];
            *(v8s*)&sV[r * LDR + c] =
                *(const v8s*)&Vh[(size_t)r * SS + kt * 64 + c];
        }
        __syncthreads();

        __builtin_amdgcn_s_setprio(1);
        v4f sc[4];
#pragma unroll
        for (int j = 0; j < 4; j++) {
            v8s b0 = *(const v8s*)&sK[(j * 16 + l16) * LDR + quad * 8];
            v8s b1 = *(const v8s*)&sK[(j * 16 + l16) * LDR + 32 + quad * 8];
            v4f t = __builtin_amdgcn_mfma_f32_16x16x32_bf16(qf[0], b0,
                                                            v4f_zero(), 0, 0, 0);
            sc[j] = __builtin_amdgcn_mfma_f32_16x16x32_bf16(qf[1], b1, t, 0, 0, 0);
        }
        __builtin_amdgcn_s_setprio(0);

        float x[4][4];
        const bool diag = (kt == qt);
#pragma unroll
        for (int j = 0; j < 4; j++) {
#pragma unroll
            for (int r = 0; r < 4; r++) {
                float v = sc[j][r] * 0.125f;
                if (diag) {
                    int kg = kt * 64 + j * 16 + l16;
                    int qg = qg_base + r;
                    if (kg > qg) v = NEG_BIG;
                }
                x[j][r] = v;
            }
        }

        float mNew[4], alpha[4];
#pragma unroll
        for (int r = 0; r < 4; r++) {
            float t = fmaxf(fmaxf(x[0][r], x[1][r]), fmaxf(x[2][r], x[3][r]));
#pragma unroll
            for (int off = 8; off >= 1; off >>= 1) t = fmaxf(t, __shfl_xor(t, off));
            mNew[r] = fmaxf(mOld[r], t);
            alpha[r] = __expf(mOld[r] - mNew[r]);
            mOld[r] = mNew[r];
        }

        short* Pw = sP[wave];
#pragma unroll
        for (int j = 0; j < 4; j++)
#pragma unroll
            for (int r = 0; r < 4; r++) {
                float p = __expf(x[j][r] - mNew[r]);
                Pw[(quad * 4 + r) * LDR + j * 16 + l16] = f2bf(p);
            }
#pragma unroll
        for (int j = 0; j < 4; j++)
#pragma unroll
            for (int r = 0; r < 4; r++) o[j][r] *= alpha[r];
#pragma unroll
        for (int r = 0; r < 4; r++) oSum[r] *= alpha[r];

        v8s pa0 = *(const v8s*)&Pw[l16 * LDR + quad * 8];
        v8s pa1 = *(const v8s*)&Pw[l16 * LDR + 32 + quad * 8];
        __builtin_amdgcn_s_setprio(1);
#pragma unroll
        for (int j = 0; j < 4; j++) {
            v8s v0 = *(const v8s*)&sV[(j * 16 + l16) * LDR + quad * 8];
            v8s v1 = *(const v8s*)&sV[(j * 16 + l16) * LDR + 32 + quad * 8];
            o[j] = __builtin_amdgcn_mfma_f32_16x16x32_bf16(pa0, v0, o[j], 0, 0, 0);
            o[j] = __builtin_amdgcn_mfma_f32_16x16x32_bf16(pa1, v1, o[j], 0, 0, 0);
        }
        oSum = __builtin_amdgcn_mfma_f32_16x16x32_bf16(pa0, onesb, oSum, 0, 0, 0);
        oSum = __builtin_amdgcn_mfma_f32_16x16x32_bf16(pa1, onesb, oSum, 0, 0, 0);
        __builtin_amdgcn_s_setprio(0);
    }

#pragma unroll
    for (int r = 0; r < 4; r++) {
        float inv = 1.f / oSum[r];
        int s = qg_base + r;
#pragma unroll
        for (int j = 0; j < 4; j++) {
            float v = o[j][r] * inv;
            Qh[(size_t)s * HD + j * 16 + l16] = f2bf(v);
        }
    }
}

// ---------------------------------------------------------------------------
extern "C" void kernel_launch(void* const* d_in, const int* in_sizes, int n_in,
                              void* d_out, int out_size, void* d_ws, size_t ws_size,
                              hipStream_t stream) {
    const float* query = (const float*)d_in[0];
    const float* key_ = (const float*)d_in[1];
    const float* value = (const float*)d_in[2];
    const float* Wq = (const float*)d_in[3];
    const float* bq = (const float*)d_in[4];
    const float* Wk = (const float*)d_in[5];
    const float* bk = (const float*)d_in[6];
    const float* Wv = (const float*)d_in[7];
    const float* bv = (const float*)d_in[8];
    const float* Wo = (const float*)d_in[9];
    const float* bo = (const float*)d_in[10];
    float* out = (float*)d_out;

    const size_t NE = (size_t)BB * SS * DD;   // 8388608
    const size_t WE = (size_t)DD * DD;        // 1048576 (one weight matrix)

    // Regions (shorts): DO0=d_out[0:NE], DO1=d_out[NE:2NE],
    //                   WS0=ws[0:NE],    WS1=ws[NE:2NE].
    short* qx  = (short*)d_out;            // DO0      [conv .. Qproj]
    short* kx  = (short*)d_out + NE;       // DO1      [conv .. Kproj]
    short* wqb = (short*)d_ws + NE;        // WS1[0:WE][conv .. Qproj] (pre-kw)
    short* wkb = (short*)d_out;            // DO0[0:WE][after Qproj .. Kproj]
    short* wvb = (short*)d_out + WE;       // DO0[WE:2WE][.. Vproj]
    short* vw  = (short*)d_out + NE;       // DO1      [Vproj .. attn] (kx dead)
    short* qw  = (short*)d_ws;             // WS0      [Qproj .. outproj]
    short* kw  = (short*)d_ws + NE;        // WS1      [Kproj .. attn]
    short* wob = (short*)d_ws + NE;        // WS1[0:WE][after attn .. outproj]

    dim3 blk(256);
    const int n8a = (int)(NE / 8);   // activation conv
    const int n8w = (int)(WE / 8);   // weight conv

    // 1) query,key -> bf16 (DO0, DO1); Wq -> bf16 (WS1, dead before kw)
    conv_bf16_kernel<<<dim3(2048), blk, 0, stream>>>(query, qx, n8a);
    conv_bf16_kernel<<<dim3(2048), blk, 0, stream>>>(key_, kx, n8a);
    conv_bf16_kernel<<<dim3(512), blk, 0, stream>>>(Wq, wqb, n8w);
    // 2) Q proj: reads DO0+WS1tail, writes WS0
    gemm_kernel<0><<<dim3(8, 64), blk, 0, stream>>>(qx, wqb, bq, qw);
    // 3) Wk -> DO0 (qx dead)
    conv_bf16_kernel<<<dim3(512), blk, 0, stream>>>(Wk, wkb, n8w);
    // 4) K proj: reads DO1+DO0head, writes WS1 (wqb dead)
    gemm_kernel<0><<<dim3(8, 64), blk, 0, stream>>>(kx, wkb, bk, kw);
    // 5) Wv -> DO0[WE:2WE]
    conv_bf16_kernel<<<dim3(512), blk, 0, stream>>>(Wv, wvb, n8w);
    // 6) V^T proj: reads DO0[WE:2WE] + value(fp32 input), writes DO1 (kx dead)
    gemm_kernel<1><<<dim3(64, 8), blk, 0, stream>>>(wvb, value, bv, vw);
    // 7) attention: reads WS0,WS1,DO1; O overwrites WS0
    attn_kernel<<<dim3(SS / 64, BB * HH), blk, 0, stream>>>(qw, kw, vw);
    // 8) Wo -> WS1 (kw dead)
    conv_bf16_kernel<<<dim3(512), blk, 0, stream>>>(Wo, wob, n8w);
    // 9) out proj: reads WS0 (O, remap) + WS1 (Wo), writes d_out fp32
    gemm_kernel<3><<<dim3(8, 64), blk, 0, stream>>>(qw, wob, bo, out);
}

// Round 6
// 463.960 us; speedup vs baseline: 1.1929x; 1.0241x over previous
//
#include <hip/hip_runtime.h>
#include <hip/hip_bf16.h>
#include <math.h>

// Problem constants
#define BB 4
#define SS 2048
#define DD 1024
#define HH 16
#define HD 64

#define NEG_BIG (-1e30f)  // finite "-inf": exp(NEG_BIG - m) == 0

// Verified facts (rounds 0-11):
//  - fp32 inputs, fp32 output; MFMA C/D layout col=lane&15,row=quad*4+reg
//  - ws_size >= 2*NE shorts (33.5 MB)
//  - r7 (cvt_pk, ones-MFMA denom, setprio): 575->504
//  - r9 (2-phase dbuf GEMM + 128-row attn): REGRESSED => don't pipeline
//    2-barrier loops at source level (m99/m100/m131-141)
//  - r10 (bf16 weights, all-gll GEMMs): 475us. attn=195us (41%).
//  - r11 (K/V+P XOR swizzle + sigma P/V layout, 3 coupled changes): FAILED
//    correctness (absmax 2528 => garbage-bits read somewhere). Could not
//    isolate statically. REVERT to r10; this round = r10 + ONE change.
// Round 12 (single variable):
//  - T2 XOR swizzle on sK/sV ONLY (stride 72->64, cs = c ^ ((r&7)<<3)).
//    The b128 B-frag reads at 144B stride were 8-way bank conflicted
//    (bank = 4*(l16+quad) mod 32). sP stays r10-verbatim (LDR=72,
//    C-layout); GEMMs and launches r10-verbatim (no sigma).

typedef short v8s __attribute__((ext_vector_type(8)));
typedef float v4f __attribute__((ext_vector_type(4)));

__device__ inline unsigned cvt_pk_bf16(float lo, float hi) {
    unsigned r;
    asm("v_cvt_pk_bf16_f32 %0, %1, %2" : "=v"(r) : "v"(lo), "v"(hi));
    return r;
}

__device__ inline short f2bf(float f) {
    return (short)cvt_pk_bf16(f, f);
}

__device__ inline v4f v4f_zero() {
    v4f z;
    z[0] = 0.f; z[1] = 0.f; z[2] = 0.f; z[3] = 0.f;
    return z;
}

__device__ inline v8s cvt8(v4f a, v4f b) {
    union { unsigned u[4]; v8s s; } x;
    x.u[0] = cvt_pk_bf16(a[0], a[1]);
    x.u[1] = cvt_pk_bf16(a[2], a[3]);
    x.u[2] = cvt_pk_bf16(b[0], b[1]);
    x.u[3] = cvt_pk_bf16(b[2], b[3]);
    return x.s;
}

__device__ inline v8s load8f(const float* p) {
    return cvt8(*(const v4f*)p, *(const v4f*)(p + 4));
}

// Async global->LDS, 16B/lane. LDS dest wave-uniform base; lane i -> base+16i.
__device__ inline void gll16(const void* g, void* l) {
    __builtin_amdgcn_global_load_lds(
        (const __attribute__((address_space(1))) unsigned*)g,
        (__attribute__((address_space(3))) unsigned*)l, 16, 0, 0);
}

// ---------------------------------------------------------------------------
// fp32 -> bf16 elementwise (vectorized, grid-stride). n8 = elems/8.
// ---------------------------------------------------------------------------
__global__ __launch_bounds__(256) void conv_bf16_kernel(
    const float* __restrict__ in, short* __restrict__ out, int n8) {
    int i = blockIdx.x * 256 + threadIdx.x;
    const int stride = gridDim.x * 256;
    for (; i < n8; i += stride) {
        *((v8s*)out + i) = load8f(in + (size_t)i * 8);
    }
}

// ---------------------------------------------------------------------------
// NT GEMM: C[M,N] = A[M,K] * B[N,K]^T + bias, fp32 accum, bf16 MFMA. K=1024.
// Single-buffer, 2 barriers per K-step (m97 structure). r10-verbatim.
// MODE 0: A act bf16 gll [8192,1024]; B wt bf16 gll; C bf16 [B,H,S,HD]. (8,64)
// MODE 1: A wt bf16 gll [1024,1024]; B value fp32 reg-staged [8192,1024];
//         C bf16 [B,H,HD,S]. grid (64,8).
// MODE 3: A O-bf16 ws remap gll; B wt bf16 gll; C fp32 row-major. (8,64)
// Tiles: BM=BN=128, BK=32. 256 thr = 4 waves (2x2), 64x64 per wave.
// ---------------------------------------------------------------------------
template <int MODE>
__global__ __launch_bounds__(256) void gemm_kernel(
    const void* __restrict__ Av, const void* __restrict__ Bv,
    const float* __restrict__ bias, void* __restrict__ Cv) {
    __shared__ short sA[128 * 32];
    __shared__ short sB[128 * 32];

    const int tid = threadIdx.x;
    const int lane = tid & 63;
    const int wave = tid >> 6;
    const int quad = lane >> 4;
    const int l16 = lane & 15;
    const int wm = wave >> 1;
    const int wn = wave & 1;

    int bx, by;
    if (MODE != 1) {
        // XCD swizzle: group the 8 n-tiles of one m-panel on one XCD
        int b = blockIdx.x + (blockIdx.y << 3);
        int l = ((b & 7) << 6) + (b >> 3);
        bx = l & 7;
        by = l >> 3;
    } else {
        bx = blockIdx.x;
        by = blockIdx.y;
    }
    const int m0 = by * 128;
    const int n0 = bx * 128;

    // gll addressing: lane i of wave w writes sX + w*1024 + i*8 shorts, which
    // is row (w*32 + i/4), col (i%4)*8 of the row-major 128x32 tile.
    const int grow = (wave << 5) + (lane >> 2);
    const int gcol = (lane & 3) << 3;
    const int ldoff = wave << 10;

    // A operand (always bf16, gll)
    const short* As = (const short*)Av;
    size_t gaA0, gaA1;
    if (MODE == 3) {
        int ma = m0 + grow, mb = m0 + grow + 16;
        gaA0 = ((size_t)((ma >> 11) * HH) * SS + (ma & 2047)) * HD;
        gaA1 = ((size_t)((mb >> 11) * HH) * SS + (mb & 2047)) * HD;
    } else {
        gaA0 = (size_t)(m0 + grow) * 1024 + gcol;
        gaA1 = gaA0 + (size_t)16 * 1024;
    }

    // B operand
    const short* Bs = (const short*)Bv;     // modes 0/3: bf16 weight, gll
    const float* Bf = (const float*)Bv;     // mode 1: fp32 value, reg-staged
    size_t gaB0 = 0, gaB1 = 0;
    if (MODE != 1) {
        gaB0 = (size_t)(n0 + grow) * 1024 + gcol;
        gaB1 = gaB0 + (size_t)16 * 1024;
    }
    const int idx0 = tid << 3, idx1 = (256 + tid) << 3;
    const float* Bsrc0 = (MODE == 1)
        ? Bf + (size_t)(n0 + (idx0 >> 5)) * 1024 + (idx0 & 31) : nullptr;
    const float* Bsrc1 = (MODE == 1)
        ? Bf + (size_t)(n0 + (idx1 >> 5)) * 1024 + (idx1 & 31) : nullptr;

    v4f acc[4][4];
#pragma unroll
    for (int i = 0; i < 4; i++)
#pragma unroll
        for (int j = 0; j < 4; j++) acc[i][j] = v4f_zero();

    for (int k0 = 0; k0 < 1024; k0 += 32) {
        __syncthreads();
        if (MODE == 3) {
            size_t hoff = (size_t)(k0 >> 6) * (SS * HD) + (k0 & 63) + gcol;
            gll16(As + gaA0 + hoff, sA + ldoff);
            gll16(As + gaA1 + hoff, sA + ldoff + 512);
        } else {
            gll16(As + gaA0 + k0, sA + ldoff);
            gll16(As + gaA1 + k0, sA + ldoff + 512);
        }
        if (MODE == 1) {
            *(v8s*)&sB[idx0] = load8f(Bsrc0 + k0);
            *(v8s*)&sB[idx1] = load8f(Bsrc1 + k0);
        } else {
            gll16(Bs + gaB0 + k0, sB + ldoff);
            gll16(Bs + gaB1 + k0, sB + ldoff + 512);
        }
        __syncthreads();

        v8s af[4], bfr[4];
#pragma unroll
        for (int i = 0; i < 4; i++)
            af[i] = *(const v8s*)&sA[(wm * 64 + i * 16 + l16) * 32 + quad * 8];
#pragma unroll
        for (int j = 0; j < 4; j++)
            bfr[j] = *(const v8s*)&sB[(wn * 64 + j * 16 + l16) * 32 + quad * 8];
#pragma unroll
        for (int i = 0; i < 4; i++)
#pragma unroll
            for (int j = 0; j < 4; j++)
                acc[i][j] = __builtin_amdgcn_mfma_f32_16x16x32_bf16(
                    af[i], bfr[j], acc[i][j], 0, 0, 0);
    }

    // Epilogue: C/D layout col = lane&15, row = quad*4 + reg (HW-verified r6)
#pragma unroll
    for (int i = 0; i < 4; i++) {
#pragma unroll
        for (int j = 0; j < 4; j++) {
#pragma unroll
            for (int r = 0; r < 4; r++) {
                int ml = wm * 64 + i * 16 + quad * 4 + r;
                int nl = wn * 64 + j * 16 + l16;
                int m = m0 + ml;
                int n = n0 + nl;
                float v = acc[i][j][r];
                if (MODE == 0) {
                    v += bias[n];
                    int b = m >> 11, s = m & 2047, h = n >> 6, d = n & 63;
                    ((short*)Cv)[(((size_t)(b * HH + h) * SS + s) << 6) + d] =
                        f2bf(v);
                } else if (MODE == 1) {
                    v += bias[m];
                    int h = m >> 6, d = m & 63, b = n >> 11, s = n & 2047;
                    ((short*)Cv)[((size_t)(b * HH + h) * HD + d) * SS + s] =
                        f2bf(v);
                } else {
                    v += bias[n];
                    ((float*)Cv)[(size_t)m * 1024 + n] = v;
                }
            }
        }
    }
}

// ---------------------------------------------------------------------------
// Flash attention (causal, MFMA). Grid: (S/64, B*H). 256 thr = 4 waves.
// r10 dataflow; ONE change: sK/sV stride 72->64 with T2 XOR swizzle
// (write cs = c ^ ((r&7)<<3); reads use mask ((l16&7)<<3), valid because
// every read row is j*16+l16 so row&7 == l16&7). sP unchanged (LDR=72,
// C-layout). ones-MFMA denominator; no mid-barrier; setprio; reversed qt.
// ---------------------------------------------------------------------------
__global__ __launch_bounds__(256) void attn_kernel(
    short* __restrict__ QO, const short* __restrict__ Kt,
    const short* __restrict__ Vt) {
    constexpr int LDR = 64 + 8;           // sP stride (r10-verbatim)
    __shared__ short sK[64 * 64];
    __shared__ short sV[64 * 64];
    __shared__ short sP[4][16 * LDR];

    const int tid = threadIdx.x;
    const int lane = tid & 63;
    const int wave = tid >> 6;
    const int quad = lane >> 4;
    const int l16 = lane & 15;
    const int qt = (int)gridDim.x - 1 - (int)blockIdx.x;
    const int bh = blockIdx.y;

    short* Qh = QO + (size_t)bh * SS * HD;
    const short* Kh = Kt + (size_t)bh * SS * HD;
    const short* Vh = Vt + (size_t)bh * HD * SS;

    const int qrow = qt * 64 + wave * 16 + l16;
    v8s qf[2];
    qf[0] = *(const v8s*)&Qh[(size_t)qrow * HD + quad * 8];
    qf[1] = *(const v8s*)&Qh[(size_t)qrow * HD + 32 + quad * 8];

    v8s onesb;
#pragma unroll
    for (int i = 0; i < 8; i++) onesb[i] = (short)0x3F80;  // bf16 1.0

    v4f o[4];
#pragma unroll
    for (int j = 0; j < 4; j++) o[j] = v4f_zero();
    v4f oSum = v4f_zero();
    float mOld[4];
#pragma unroll
    for (int r = 0; r < 4; r++) mOld[r] = NEG_BIG;

    const int qg_base = qt * 64 + wave * 16 + quad * 4;

    // swizzled column offsets (shorts) for sK/sV reads; read row = j*16+l16
    // => row&7 == l16&7, matching the write-side mask (r&7)<<3.
    const int rc0 = (quad * 8) ^ ((l16 & 7) << 3);
    const int rc1 = (32 + quad * 8) ^ ((l16 & 7) << 3);

    for (int kt = 0; kt <= qt; kt++) {
        __syncthreads();
#pragma unroll
        for (int p = 0; p < 2; p++) {
            int idx = (p * 256 + tid) * 8;
            int r = idx >> 6;
            int c = idx & 63;
            int cs = c ^ ((r & 7) << 3);  // T2 XOR swizzle
            *(v8s*)&sK[r * 64 + cs] =
                *(const v8s*)&Kh[(size_t)(kt * 64 + r) * HD + c];
            *(v8s*)&sV[r * 64 + cs] =
                *(const v8s*)&Vh[(size_t)r * SS + kt * 64 + c];
        }
        __syncthreads();

        __builtin_amdgcn_s_setprio(1);
        v4f sc[4];
#pragma unroll
        for (int j = 0; j < 4; j++) {
            v8s b0 = *(const v8s*)&sK[(j * 16 + l16) * 64 + rc0];
            v8s b1 = *(const v8s*)&sK[(j * 16 + l16) * 64 + rc1];
            v4f t = __builtin_amdgcn_mfma_f32_16x16x32_bf16(qf[0], b0,
                                                            v4f_zero(), 0, 0, 0);
            sc[j] = __builtin_amdgcn_mfma_f32_16x16x32_bf16(qf[1], b1, t, 0, 0, 0);
        }
        __builtin_amdgcn_s_setprio(0);

        float x[4][4];
        const bool diag = (kt == qt);
#pragma unroll
        for (int j = 0; j < 4; j++) {
#pragma unroll
            for (int r = 0; r < 4; r++) {
                float v = sc[j][r] * 0.125f;
                if (diag) {
                    int kg = kt * 64 + j * 16 + l16;
                    int qg = qg_base + r;
                    if (kg > qg) v = NEG_BIG;
                }
                x[j][r] = v;
            }
        }

        float mNew[4], alpha[4];
#pragma unroll
        for (int r = 0; r < 4; r++) {
            float t = fmaxf(fmaxf(x[0][r], x[1][r]), fmaxf(x[2][r], x[3][r]));
#pragma unroll
            for (int off = 8; off >= 1; off >>= 1) t = fmaxf(t, __shfl_xor(t, off));
            mNew[r] = fmaxf(mOld[r], t);
            alpha[r] = __expf(mOld[r] - mNew[r]);
            mOld[r] = mNew[r];
        }

        // P -> sP in C layout (r10-verbatim, LDR=72, unswizzled)
        short* Pw = sP[wave];
#pragma unroll
        for (int j = 0; j < 4; j++)
#pragma unroll
            for (int r = 0; r < 4; r++) {
                float p = __expf(x[j][r] - mNew[r]);
                Pw[(quad * 4 + r) * LDR + j * 16 + l16] = f2bf(p);
            }
#pragma unroll
        for (int j = 0; j < 4; j++)
#pragma unroll
            for (int r = 0; r < 4; r++) o[j][r] *= alpha[r];
#pragma unroll
        for (int r = 0; r < 4; r++) oSum[r] *= alpha[r];

        // PV (+ ones-MFMA denominator); same-wave ds order guards sP reuse
        v8s pa0 = *(const v8s*)&Pw[l16 * LDR + quad * 8];
        v8s pa1 = *(const v8s*)&Pw[l16 * LDR + 32 + quad * 8];
        __builtin_amdgcn_s_setprio(1);
#pragma unroll
        for (int j = 0; j < 4; j++) {
            v8s v0 = *(const v8s*)&sV[(j * 16 + l16) * 64 + rc0];
            v8s v1 = *(const v8s*)&sV[(j * 16 + l16) * 64 + rc1];
            o[j] = __builtin_amdgcn_mfma_f32_16x16x32_bf16(pa0, v0, o[j], 0, 0, 0);
            o[j] = __builtin_amdgcn_mfma_f32_16x16x32_bf16(pa1, v1, o[j], 0, 0, 0);
        }
        oSum = __builtin_amdgcn_mfma_f32_16x16x32_bf16(pa0, onesb, oSum, 0, 0, 0);
        oSum = __builtin_amdgcn_mfma_f32_16x16x32_bf16(pa1, onesb, oSum, 0, 0, 0);
        __builtin_amdgcn_s_setprio(0);
    }

#pragma unroll
    for (int r = 0; r < 4; r++) {
        float inv = 1.f / oSum[r];
        int s = qg_base + r;
#pragma unroll
        for (int j = 0; j < 4; j++) {
            float v = o[j][r] * inv;
            Qh[(size_t)s * HD + j * 16 + l16] = f2bf(v);
        }
    }
}

// ---------------------------------------------------------------------------
extern "C" void kernel_launch(void* const* d_in, const int* in_sizes, int n_in,
                              void* d_out, int out_size, void* d_ws, size_t ws_size,
                              hipStream_t stream) {
    const float* query = (const float*)d_in[0];
    const float* key_ = (const float*)d_in[1];
    const float* value = (const float*)d_in[2];
    const float* Wq = (const float*)d_in[3];
    const float* bq = (const float*)d_in[4];
    const float* Wk = (const float*)d_in[5];
    const float* bk = (const float*)d_in[6];
    const float* Wv = (const float*)d_in[7];
    const float* bv = (const float*)d_in[8];
    const float* Wo = (const float*)d_in[9];
    const float* bo = (const float*)d_in[10];
    float* out = (float*)d_out;

    const size_t NE = (size_t)BB * SS * DD;   // 8388608
    const size_t WE = (size_t)DD * DD;        // 1048576 (one weight matrix)

    // Regions (shorts): DO0=d_out[0:NE], DO1=d_out[NE:2NE],
    //                   WS0=ws[0:NE],    WS1=ws[NE:2NE].
    short* qx  = (short*)d_out;            // DO0      [conv .. Qproj]
    short* kx  = (short*)d_out + NE;       // DO1      [conv .. Kproj]
    short* wqb = (short*)d_ws + NE;        // WS1[0:WE][conv .. Qproj] (pre-kw)
    short* wkb = (short*)d_out;            // DO0[0:WE][after Qproj .. Kproj]
    short* wvb = (short*)d_out + WE;       // DO0[WE:2WE][.. Vproj]
    short* vw  = (short*)d_out + NE;       // DO1      [Vproj .. attn] (kx dead)
    short* qw  = (short*)d_ws;             // WS0      [Qproj .. outproj]
    short* kw  = (short*)d_ws + NE;        // WS1      [Kproj .. attn]
    short* wob = (short*)d_ws + NE;        // WS1[0:WE][after attn .. outproj]

    dim3 blk(256);
    const int n8a = (int)(NE / 8);   // activation conv
    const int n8w = (int)(WE / 8);   // weight conv

    // 1) query,key -> bf16 (DO0, DO1); Wq -> bf16 (WS1, dead before kw)
    conv_bf16_kernel<<<dim3(2048), blk, 0, stream>>>(query, qx, n8a);
    conv_bf16_kernel<<<dim3(2048), blk, 0, stream>>>(key_, kx, n8a);
    conv_bf16_kernel<<<dim3(512), blk, 0, stream>>>(Wq, wqb, n8w);
    // 2) Q proj: reads DO0+WS1tail, writes WS0
    gemm_kernel<0><<<dim3(8, 64), blk, 0, stream>>>(qx, wqb, bq, qw);
    // 3) Wk -> DO0 (qx dead)
    conv_bf16_kernel<<<dim3(512), blk, 0, stream>>>(Wk, wkb, n8w);
    // 4) K proj: reads DO1+DO0head, writes WS1 (wqb dead)
    gemm_kernel<0><<<dim3(8, 64), blk, 0, stream>>>(kx, wkb, bk, kw);
    // 5) Wv -> DO0[WE:2WE]
    conv_bf16_kernel<<<dim3(512), blk, 0, stream>>>(Wv, wvb, n8w);
    // 6) V^T proj: reads DO0[WE:2WE] + value(fp32 input), writes DO1 (kx dead)
    gemm_kernel<1><<<dim3(64, 8), blk, 0, stream>>>(wvb, value, bv, vw);
    // 7) attention: reads WS0,WS1,DO1; O overwrites WS0
    attn_kernel<<<dim3(SS / 64, BB * HH), blk, 0, stream>>>(qw, kw, vw);
    // 8) Wo -> WS1 (kw dead)
    conv_bf16_kernel<<<dim3(512), blk, 0, stream>>>(Wo, wob, n8w);
    // 9) out proj: reads WS0 (O, remap) + WS1 (Wo), writes d_out fp32
    gemm_kernel<3><<<dim3(8, 64), blk, 0, stream>>>(qw, wob, bo, out);
}